// Round 7
// baseline (1771.741 us; speedup 1.0000x reference)
//
#include <hip/hip_runtime.h>
#include <math.h>

#define BATCH 32
#define TFRAMES 1024
#define NBINS 257
#define NFFT 512
#define HOP 160
#define LOUT 163680
#define XPLEN 164192
#define NITER 32
#define FPW 4                        // frames per wave
#define WSTRIDE (FPW*HOP)            // 640
#define BSTRIDE (2*WSTRIDE)          // 1280 (block = 2 waves = 8 frames)
#define HALO (NFFT-HOP)              // 352
#define WSPAN (WSTRIDE+HALO)         // 992  per-wave OLA span
#define SPAN (BSTRIDE+HALO)          // 1632 per-block OLA span
#define NBLK 128                     // blocks per batch row
#define SLOT SPAN
#define SB ((size_t)NBLK*SLOT)
#define SBUF ((size_t)BATCH*SB)

#define P(i) ((i) + ((i) >> 5))      // LDS pad (k_inv0s legacy FFT only)

__device__ __forceinline__ float cosr(float x){ return __builtin_amdgcn_cosf(x); }
__device__ __forceinline__ float sinr(float x){ return __builtin_amdgcn_sinf(x); }
__device__ __forceinline__ void wsync(){
    __builtin_amdgcn_fence(__ATOMIC_SEQ_CST, "wavefront");
    __builtin_amdgcn_wave_barrier();
}
// xor-shuffle within 32-lane halves (d<32), full-wave via bpermute (d>=32)
#define SWZ(v, d) __int_as_float(__builtin_amdgcn_ds_swizzle(__float_as_int(v), (((d)<<10)|0x1F)))
__device__ __forceinline__ float bperm(int addr, float v){
    return __int_as_float(__builtin_amdgcn_ds_bpermute(addr, __float_as_int(v)));
}

struct Tw { float c1,s1,c2,s2,c3,s3; };
__device__ __forceinline__ Tw twset(float x){
    Tw t; float c=cosr(x), s=sinr(x);
    t.c1=c; t.s1=s;
    t.c2=c*c-s*s; t.s2=2.f*c*s;
    t.c3=t.c2*c-t.s2*s; t.s3=t.c2*s+t.s2*c;
    return t;
}

template<int SIGN, bool TWID>
__device__ __forceinline__ void bfly4(const float xr[4], const float xi[4],
                                      const Tw& t, float yr[4], float yi[4]){
    constexpr float SG = (SIGN>0)?1.f:-1.f;
    float apc_r=xr[0]+xr[2], apc_i=xi[0]+xi[2];
    float amc_r=xr[0]-xr[2], amc_i=xi[0]-xi[2];
    float bpd_r=xr[1]+xr[3], bpd_i=xi[1]+xi[3];
    float bmd_r=xr[1]-xr[3], bmd_i=xi[1]-xi[3];
    yr[0]=apc_r+bpd_r; yi[0]=apc_i+bpd_i;
    float u2r=apc_r-bpd_r, u2i=apc_i-bpd_i;
    float u1r=amc_r-SG*bmd_i, u1i=amc_i+SG*bmd_r;
    float u3r=amc_r+SG*bmd_i, u3i=amc_i-SG*bmd_r;
    if (TWID){
        float s1=SG*t.s1, s2=SG*t.s2, s3=SG*t.s3;
        yr[1]=t.c1*u1r-s1*u1i; yi[1]=t.c1*u1i+s1*u1r;
        yr[2]=t.c2*u2r-s2*u2i; yi[2]=t.c2*u2i+s2*u2r;
        yr[3]=t.c3*u3r-s3*u3i; yi[3]=t.c3*u3i+s3*u3r;
    } else {
        yr[1]=u1r; yi[1]=u1i; yr[2]=u2r; yi[2]=u2i; yr[3]=u3r; yi[3]=u3i;
    }
}

// per-lane constants for the cross-lane FFT64 (6 radix-2 xor stages)
struct LTw {
    float c32,t32,c16,t16,c8,t8,c4,t4,c2,t2;   // fwd factors (cos, -sin)
    float g32,g16,g8,g4,g2,g1;                  // sumdiff signs
};
__device__ __forceinline__ LTw ltw_init(int l){
    LTw L; float t;
    t = (l&32)? (float)(l&31)*(1.f/64.f) : 0.f; L.c32=cosr(t); L.t32=-sinr(t);
    t = (l&16)? (float)(l&15)*(1.f/32.f) : 0.f; L.c16=cosr(t); L.t16=-sinr(t);
    t = (l&8) ? (float)(l&7) *(1.f/16.f) : 0.f; L.c8 =cosr(t); L.t8 =-sinr(t);
    t = (l&4) ? (float)(l&3) *(1.f/8.f)  : 0.f; L.c4 =cosr(t); L.t4 =-sinr(t);
    t = (l&2) ? (float)(l&1) *(1.f/4.f)  : 0.f; L.c2 =cosr(t); L.t2 =-sinr(t);
    L.g32=(l&32)?-1.f:1.f; L.g16=(l&16)?-1.f:1.f; L.g8=(l&8)?-1.f:1.f;
    L.g4 =(l&4) ?-1.f:1.f; L.g2 =(l&2) ?-1.f:1.f; L.g1=(l&1)?-1.f:1.f;
    return L;
}

// forward FFT64 over lanes (DIF, natural in -> bitrev6 lane order out)
__device__ __forceinline__ void f64fwd(float& r, float& i, const LTw& L, int a32){
    float vr, vi, ur, ui;
    vr = bperm(a32, r); vi = bperm(a32, i);
    ur = fmaf(L.g32, r, vr); ui = fmaf(L.g32, i, vi);
    r = L.c32*ur - L.t32*ui; i = L.c32*ui + L.t32*ur;
    vr = SWZ(r,16); vi = SWZ(i,16);
    ur = fmaf(L.g16, r, vr); ui = fmaf(L.g16, i, vi);
    r = L.c16*ur - L.t16*ui; i = L.c16*ui + L.t16*ur;
    vr = SWZ(r,8); vi = SWZ(i,8);
    ur = fmaf(L.g8, r, vr); ui = fmaf(L.g8, i, vi);
    r = L.c8*ur - L.t8*ui; i = L.c8*ui + L.t8*ur;
    vr = SWZ(r,4); vi = SWZ(i,4);
    ur = fmaf(L.g4, r, vr); ui = fmaf(L.g4, i, vi);
    r = L.c4*ur - L.t4*ui; i = L.c4*ui + L.t4*ur;
    vr = SWZ(r,2); vi = SWZ(i,2);
    ur = fmaf(L.g2, r, vr); ui = fmaf(L.g2, i, vi);
    r = L.c2*ur - L.t2*ui; i = L.c2*ui + L.t2*ur;
    vr = SWZ(r,1); vi = SWZ(i,1);
    r = fmaf(L.g1, r, vr); i = fmaf(L.g1, i, vi);
}
// inverse (exact stage reversal, conj pre-twiddles; bitrev in -> natural out)
__device__ __forceinline__ void f64inv(float& r, float& i, const LTw& L, int a32){
    float vr, vi, ur, ui;
    vr = SWZ(r,1); vi = SWZ(i,1);
    r = fmaf(L.g1, r, vr); i = fmaf(L.g1, i, vi);
    ur = L.c2*r + L.t2*i; ui = L.c2*i - L.t2*r;
    vr = SWZ(ur,2); vi = SWZ(ui,2);
    r = fmaf(L.g2, ur, vr); i = fmaf(L.g2, ui, vi);
    ur = L.c4*r + L.t4*i; ui = L.c4*i - L.t4*r;
    vr = SWZ(ur,4); vi = SWZ(ui,4);
    r = fmaf(L.g4, ur, vr); i = fmaf(L.g4, ui, vi);
    ur = L.c8*r + L.t8*i; ui = L.c8*i - L.t8*r;
    vr = SWZ(ur,8); vi = SWZ(ui,8);
    r = fmaf(L.g8, ur, vr); i = fmaf(L.g8, ui, vi);
    ur = L.c16*r + L.t16*i; ui = L.c16*i - L.t16*r;
    vr = SWZ(ur,16); vi = SWZ(ui,16);
    r = fmaf(L.g16, ur, vr); i = fmaf(L.g16, ui, vi);
    ur = L.c32*r + L.t32*i; ui = L.c32*i - L.t32*r;
    vr = bperm(a32, ur); vi = bperm(a32, ui);
    r = fmaf(L.g32, ur, vr); i = fmaf(L.g32, ui, vi);
}

// legacy LDS Stockham FFT (k_inv0s only — runs once)
template<int SIGN>
__device__ __forceinline__ void fft256reg(float xr[4], float xi[4],
                                          float* br, float* bi,
                                          const Tw& tw0, const Tw& tw1, const Tw& tw2,
                                          int lane){
    float yr[4], yi[4], ar[4], ai[4];
    bfly4<SIGN,true>(xr, xi, tw0, yr, yi);
    { int o = 4*lane;
#pragma unroll
      for (int c=0;c<4;++c){ br[P(o+c)]=yr[c]; bi[P(o+c)]=yi[c]; } }
    wsync();
#pragma unroll
    for (int c=0;c<4;++c){ ar[c]=br[P(lane+64*c)]; ai[c]=bi[P(lane+64*c)]; }
    wsync();
    bfly4<SIGN,true>(ar, ai, tw1, yr, yi);
    { int o = (lane&3) + 16*(lane>>2);
#pragma unroll
      for (int c=0;c<4;++c){ br[P(o+4*c)]=yr[c]; bi[P(o+4*c)]=yi[c]; } }
    wsync();
#pragma unroll
    for (int c=0;c<4;++c){ ar[c]=br[P(lane+64*c)]; ai[c]=bi[P(lane+64*c)]; }
    wsync();
    bfly4<SIGN,true>(ar, ai, tw2, yr, yi);
    { int o = (lane&15) + 64*(lane>>4);
#pragma unroll
      for (int c=0;c<4;++c){ br[P(o+16*c)]=yr[c]; bi[P(o+16*c)]=yi[c]; } }
    wsync();
#pragma unroll
    for (int c=0;c<4;++c){ ar[c]=br[P(lane+64*c)]; ai[c]=bi[P(lane+64*c)]; }
    wsync();
    bfly4<SIGN,false>(ar, ai, tw0, xr, xi);
}

// ============================================================
__global__ __launch_bounds__(256) void k_init(const float* __restrict__ win,
                                              float* __restrict__ wsqi){
    int i = blockIdx.x*256 + threadIdx.x;
    if (i < XPLEN){
        int n = i;
        int tmax = n / HOP; if (tmax > TFRAMES-1) tmax = TFRAMES-1;
        int tmin = (n - (NFFT-1) + (HOP-1)) / HOP; if (tmin < 0) tmin = 0;
        float acc = 0.f;
        for (int t = tmin; t <= tmax; ++t){ float w = win[n - t*HOP]; acc += w*w; }
        wsqi[i] = 1.0f / (acc > 1e-11f ? acc : 1.0f);
    }
}

// slot-reconstructed signal reads
__device__ __forceinline__ float xs(const float* __restrict__ Sb,
                                    const float* __restrict__ wsq, int p){
    int bxp = p / BSTRIDE, r = p - bxp*BSTRIDE;
    float a = 0.f;
    if (bxp < NBLK) a = Sb[(size_t)bxp*SLOT + r];
    if (r < HALO && bxp > 0) a += Sb[(size_t)(bxp-1)*SLOT + BSTRIDE + r];
    return a * wsq[p];
}
__device__ __forceinline__ float2 xs2(const float* __restrict__ Sb,
                                      const float* __restrict__ wsq, int p){ // p even
    int bxp = p / BSTRIDE, r = p - bxp*BSTRIDE;
    float2 acc = make_float2(0.f, 0.f);
    if (bxp < NBLK) acc = *(const float2*)(Sb + (size_t)bxp*SLOT + r);
    if (r < HALO && bxp > 0){
        float2 h = *(const float2*)(Sb + (size_t)(bxp-1)*SLOT + BSTRIDE + r);
        acc.x += h.x; acc.y += h.y;
    }
    float2 q = *(const float2*)(wsq + p);
    return make_float2(acc.x*q.x, acc.y*q.y);
}

// legacy inverse tail for k_inv0s
__device__ __forceinline__ void inv_accum(float pr[4], float pi[4],
                                          float* br, float* bi,
                                          const Tw& tw0, const Tw& tw1, const Tw& tw2,
                                          const float wA[4], const float wB[4],
                                          int lane, int f, float2* sa2){
    fft256reg<+1>(pr, pi, br, bi, tw0, tw1, tw2, lane);
    constexpr float SC = 1.f/256.f;
    int base2 = f*(HOP/2);
#pragma unroll
    for (int c=0;c<4;++c){
        int u = base2 + lane + 64*c;
        float2 v = sa2[u];
        v.x += pr[c]*wA[c]*SC;
        v.y += pi[c]*wB[c]*SC;
        sa2[u] = v;
    }
    wsync();
}

__device__ __forceinline__ void slot_store(float* __restrict__ Sw, int b, int bx,
                                           const float* s0, const float* s1, int tid){
    float2* slot2 = (float2*)(Sw + ((size_t)b*NBLK + bx)*SLOT);
    const float2* s0_2 = (const float2*)s0;
    const float2* s1_2 = (const float2*)s1;
#pragma unroll
    for (int j=0;j<7;++j){
        int u = tid + 128*j;
        if (u < SPAN/2){
            float2 v = make_float2(0.f, 0.f);
            if (u < WSPAN/2) v = s0_2[u];
            if (u >= WSTRIDE/2){
                float2 w1 = s1_2[u - WSTRIDE/2];
                v.x += w1.x; v.y += w1.y;
            }
            slot2[u] = v;
        }
    }
}

// ============================================================
// k_gl: one Griffin-Lim iteration, register-resident shuffle FFT.
// ============================================================
__global__ __launch_bounds__(128,4) void k_gl(const float* __restrict__ Sr,
                                              float* __restrict__ Sw,
                                              const float* __restrict__ mag,
                                              const float* __restrict__ win,
                                              const float* __restrict__ wsq){
    __shared__ __align__(16) float sacc[2][WSPAN];
    int tid = threadIdx.x, w = tid>>6, lane = tid&63;
    int b = blockIdx.y, bx = blockIdx.x;
    float2* sa2 = (float2*)sacc[w];

    Tw tw0 = twset((float)lane * (1.f/256.f));
    LTw L = ltw_init(lane);
    int a32 = (lane^32) << 2;
    int a63 = (lane^63) << 2;
    int mrev = (int)(__builtin_bitreverse32((unsigned)lane) >> 26);
    int mm = (64 - mrev) & 63;
    int a0 = (int)((__builtin_bitreverse32((unsigned)mm) >> 26) << 2);
    int k1[4]; float twc[4], tws[4], wA[4], wB[4];
#pragma unroll
    for (int j=0;j<4;++j){
        k1[j] = 4*mrev + j;
        float x = (float)k1[j] * (1.f/512.f);
        twc[j]=cosr(x); tws[j]=sinr(x);
        float2 wv = ((const float2*)win)[lane + 64*j];
        wA[j]=wv.x; wB[j]=wv.y;
    }
#pragma unroll
    for (int j=0;j<8;++j){ int u = lane + 64*j; if (u < WSPAN/2) sa2[u]=make_float2(0.f,0.f); }

    const float* Sb = Sr + (size_t)b*SB;
    const float* magb = mag + ((size_t)b*TFRAMES)*NBINS;
    int t0 = (bx*2 + w)*FPW;

#pragma unroll 1
    for (int f=0; f<FPW; ++f){
        int t = t0 + f;
        const float* magp = magb + (size_t)t*NBINS;
        // early mag gathers (hide latency behind the forward FFT)
        float m1[4], m2[4];
#pragma unroll
        for (int j=0;j<4;++j){ m1[j] = magp[k1[j]]; m2[j] = magp[256 - k1[j]]; }

        float fr[4], fi[4];
        bool edge = (t < 2) | (t >= TFRAMES-2);
        if (!edge){
            int pb = t*HOP;
#pragma unroll
            for (int c=0;c<4;++c){
                int p = pb + 2*(lane + 64*c);
                float2 v = xs2(Sb, wsq, p);
                fr[c] = v.x*wA[c];
                fi[c] = v.y*wB[c];
            }
        } else {
#pragma unroll
            for (int c=0;c<4;++c){
                int m = lane + 64*c;
                int p0 = t*HOP + 2*m, p1 = p0+1;
                int n0 = (p0<256)?(512-p0):((p0>=LOUT+256)?(2*LOUT+510-p0):p0);
                int n1 = (p1<256)?(512-p1):((p1>=LOUT+256)?(2*LOUT+510-p1):p1);
                fr[c] = xs(Sb, wsq, n0)*wA[c];
                fi[c] = xs(Sb, wsq, n1)*wB[c];
            }
        }
        // forward: in-reg radix-4 (stride 64) then 4x FFT64 across lanes
        float ur[4], ui[4];
        bfly4<-1,true>(fr, fi, tw0, ur, ui);
#pragma unroll
        for (int j=0;j<4;++j) f64fwd(ur[j], ui[j], L, a32);
        // mirror partner pulls: element (j,m) <-> (4-j, 63-m) [reg swap 1<->3],
        // j=0 partner via precomputed bitrev address (lane0 = self = Nyquist path)
        float yr[4], yi[4];
        yr[0]=bperm(a0,  ur[0]); yi[0]=bperm(a0,  ui[0]);
        yr[1]=bperm(a63, ur[3]); yi[1]=bperm(a63, ui[3]);
        yr[2]=bperm(a63, ur[2]); yi[2]=bperm(a63, ui[2]);
        yr[3]=bperm(a63, ur[1]); yi[3]=bperm(a63, ui[1]);
        float pr[4], pi[4];
#pragma unroll
        for (int j=0;j<4;++j){
            float zr = ur[j], zi = ui[j];
            float Xer = 0.5f*(zr+yr[j]), Xei = 0.5f*(zi-yi[j]);
            float Dr = zr-yr[j], Di = zi+yi[j];
            float Xor = 0.5f*Di, Xoi = -0.5f*Dr;
            float Or = twc[j]*Xor + tws[j]*Xoi;
            float Oi = twc[j]*Xoi - tws[j]*Xor;
            float X1r = Xer + Or, X1i = Xei + Oi;
            float X2r = Xer - Or, X2i = Oi - Xei;
            float q1 = X1r*X1r + X1i*X1i;
            bool ok1 = q1 > 1e-30f;
            float v1 = ok1 ? __builtin_amdgcn_rsqf(q1) : 0.f;
            float c1 = ok1 ? X1r*v1 : 1.f, s1 = X1i*v1;
            float q2 = X2r*X2r + X2i*X2i;
            bool ok2 = q2 > 1e-30f;
            float v2 = ok2 ? __builtin_amdgcn_rsqf(q2) : 0.f;
            float c2 = ok2 ? X2r*v2 : 1.f, s2 = X2i*v2;
            float S1r = m1[j]*c1, S1i = m1[j]*s1;
            float S2r = m2[j]*c2, S2i = m2[j]*s2;
            float Aer = 0.5f*(S1r+S2r), Aei = 0.5f*(S1i-S2i);
            float Er = S1r - S2r, Ei = S1i + S2i;
            float Bor = 0.5f*(twc[j]*Er - tws[j]*Ei);
            float Boi = 0.5f*(twc[j]*Ei + tws[j]*Er);
            pr[j] = Aer - Boi;
            pi[j] = Aei + Bor;
        }
        // inverse: 4x inv FFT64 (consumes bitrev), conj pre-twiddle, in-reg radix-4
#pragma unroll
        for (int j=0;j<4;++j) f64inv(pr[j], pi[j], L, a32);
        float tr[4], ti[4];
        tr[0]=pr[0]; ti[0]=pi[0];
        tr[1]=tw0.c1*pr[1]-tw0.s1*pi[1]; ti[1]=tw0.c1*pi[1]+tw0.s1*pr[1];
        tr[2]=tw0.c2*pr[2]-tw0.s2*pi[2]; ti[2]=tw0.c2*pi[2]+tw0.s2*pr[2];
        tr[3]=tw0.c3*pr[3]-tw0.s3*pi[3]; ti[3]=tw0.c3*pi[3]+tw0.s3*pr[3];
        float zr2[4], zi2[4];
        bfly4<+1,false>(tr, ti, tw0, zr2, zi2);
        constexpr float SC = 1.f/256.f;
        int base2 = f*(HOP/2);
#pragma unroll
        for (int q=0;q<4;++q){
            int u = base2 + lane + 64*q;
            float2 v = sa2[u];
            v.x += zr2[q]*wA[q]*SC;
            v.y += zi2[q]*wB[q]*SC;
            sa2[u] = v;
        }
    }
    __syncthreads();
    slot_store(Sw, b, bx, sacc[0], sacc[1], tid);
}

// ============================================================
// k_inv0s: iteration-0 istft from (mag, angles_init) -> slots (legacy path)
// ============================================================
__global__ __launch_bounds__(128,4) void k_inv0s(const float* __restrict__ mag,
                                                 const float* __restrict__ ang,
                                                 const float* __restrict__ win,
                                                 float* __restrict__ Sw){
    __shared__ __align__(16) float sacc[2][WSPAN];
    __shared__ __align__(16) float FR[2][272], FI[2][272];
    int tid = threadIdx.x, w = tid>>6, lane = tid&63;
    int b = blockIdx.y, bx = blockIdx.x;

    float *br = FR[w], *bi = FI[w];
    float2* sa2 = (float2*)sacc[w];

    Tw tw0 = twset((float)lane * (1.f/256.f));
    Tw tw1 = twset((float)(lane>>2) * (1.f/64.f));
    Tw tw2 = twset((float)(lane>>4) * (1.f/16.f));
    float twc[4], tws[4], wA[4], wB[4];
#pragma unroll
    for (int c=0;c<4;++c){
        int k = lane + 64*c;
        float x = (float)k * (1.f/512.f);
        twc[c]=cosr(x); tws[c]=sinr(x);
        float2 wv = ((const float2*)win)[k];
        wA[c]=wv.x; wB[c]=wv.y;
    }
#pragma unroll
    for (int j=0;j<8;++j){ int u = lane + 64*j; if (u < WSPAN/2) sa2[u]=make_float2(0.f,0.f); }
    __syncthreads();

    const float* magb = mag + ((size_t)b*TFRAMES)*NBINS;
    const float* angb = ang + ((size_t)b*TFRAMES)*NBINS;
    int t0 = (bx*2 + w)*FPW;

#pragma unroll 1
    for (int f=0; f<FPW; ++f){
        int t = t0 + f;
        const float* magp = magb + (size_t)t*NBINS;
        const float* angp = angb + (size_t)t*NBINS;
        float sr_[4], si_[4];
#pragma unroll
        for (int c=0;c<4;++c){
            int k = lane + 64*c;
            float m = magp[k], a = angp[k];
            float sn, cs;
            sincosf(a, &sn, &cs);
            sr_[c] = m*cs;
            si_[c] = (c==0 && lane==0) ? 0.f : m*sn;
        }
#pragma unroll
        for (int c=0;c<4;++c){ int k=lane+64*c; br[P(k)]=sr_[c]; bi[P(k)]=si_[c]; }
        if (lane==0){
            br[P(256)] = magp[256]*cosf(angp[256]);
            bi[P(256)] = 0.f;
        }
        wsync();
        float pr[4], pi[4];
#pragma unroll
        for (int c=0;c<4;++c){
            int k = lane + 64*c;
            float yr = br[P(256-k)], yi = bi[P(256-k)];
            float Aer = 0.5f*(sr_[c]+yr), Aei = 0.5f*(si_[c]-yi);
            float Er = sr_[c]-yr, Ei = si_[c]+yi;
            float Bor = 0.5f*(twc[c]*Er - tws[c]*Ei);
            float Boi = 0.5f*(twc[c]*Ei + tws[c]*Er);
            pr[c] = Aer - Boi;
            pi[c] = Aei + Bor;
        }
        wsync();
        inv_accum(pr, pi, br, bi, tw0, tw1, tw2, wA, wB, lane, f, sa2);
    }
    __syncthreads();
    slot_store(Sw, b, bx, sacc[0], sacc[1], tid);
}

// ============================================================
__global__ __launch_bounds__(128) void k_out(const float* __restrict__ S,
                                             const float* __restrict__ wsq,
                                             float* __restrict__ out){
    int b = blockIdx.y;
    int idx = blockIdx.x*128 + threadIdx.x;
    if (idx >= LOUT/2) return;
    const float* Sb = S + (size_t)b*SB;
    float2 v = xs2(Sb, wsq, 256 + 2*idx);
    ((float2*)(out + (size_t)b*LOUT))[idx] = v;
}

// ============================================================
extern "C" void kernel_launch(void* const* d_in, const int* in_sizes, int n_in,
                              void* d_out, int out_size, void* d_ws, size_t ws_size,
                              hipStream_t stream) {
    const float* mag  = (const float*)d_in[0];
    const float* ang0 = (const float*)d_in[1];
    const float* win  = (const float*)d_in[2];
    float* ws = (float*)d_ws;
    float* S[2] = { ws, ws + SBUF };
    float* wsqi = ws + 2*SBUF;
    float* outp = (float*)d_out;

    k_init<<<(XPLEN + 255)/256, 256, 0, stream>>>(win, wsqi);

    dim3 g(NBLK, BATCH);
    k_inv0s<<<g, 128, 0, stream>>>(mag, ang0, win, S[0]);
    for (int it = 0; it < NITER; ++it){
        k_gl<<<g, 128, 0, stream>>>(S[it%2], S[(it+1)%2], mag, win, wsqi);
    }
    k_out<<<dim3(640, BATCH), 128, 0, stream>>>(S[NITER%2], wsqi, outp);
}